// Round 5
// baseline (270.557 us; speedup 1.0000x reference)
//
#include <hip/hip_runtime.h>
#include <hip/hip_bf16.h>
#include <stdint.h>

#define T_TOK 2048
#define HDIM  1024
#define IDIM  768
#define NEXP  32
#define TOPK  4
#define NPAIR (T_TOK*TOPK)   // 8192
#define MTILE 256
#define MAXMT 64

typedef __attribute__((ext_vector_type(8))) short bf16x8;
typedef __attribute__((ext_vector_type(4))) float f32x4;

typedef __attribute__((address_space(1))) const unsigned int gu32;
typedef __attribute__((address_space(3))) unsigned int lu32;

__device__ __forceinline__ void gload_lds16(const void* g, void* l){
  __builtin_amdgcn_global_load_lds((gu32*)g, (lu32*)l, 16, 0, 0);
}

__device__ __forceinline__ unsigned short f2bf(float f){
  union { float f; unsigned u; } v; v.f = f;
  unsigned r = (v.u + 0x7fffu + ((v.u >> 16) & 1u)) >> 16;  // RNE
  return (unsigned short)r;
}

// ---------------- x fp32 -> bf16 ----------------
__global__ __launch_bounds__(256) void k_convert_x(const float* __restrict__ x,
                                                   ushort* __restrict__ xb){
  int idx = blockIdx.x*256 + threadIdx.x;
  float4 v = ((const float4*)x)[idx];
  ushort4 o; o.x=f2bf(v.x); o.y=f2bf(v.y); o.z=f2bf(v.z); o.w=f2bf(v.w);
  ((ushort4*)xb)[idx] = o;
}

// ---------------- router ----------------
__global__ __launch_bounds__(256) void k_router(const float* __restrict__ x,
                                                const float* __restrict__ gw,
                                                int* __restrict__ ei, float* __restrict__ wv,
                                                int* __restrict__ counts){
  int wid  = threadIdx.x >> 6;
  int lane = threadIdx.x & 63;
  int t = blockIdx.x*4 + wid;
  float xv[16];
  #pragma unroll
  for (int i=0;i<16;i++) xv[i] = x[t*HDIM + i*64 + lane];
  float p[NEXP];
  #pragma unroll
  for (int e=0;e<NEXP;e++){
    const float* w = gw + e*HDIM;
    float a = 0.f;
    #pragma unroll
    for (int i=0;i<16;i++) a = fmaf(xv[i], w[i*64+lane], a);
    #pragma unroll
    for (int off=32; off>=1; off>>=1) a += __shfl_xor(a, off, 64);
    p[e] = a;
  }
  float m = p[0];
  #pragma unroll
  for (int e=1;e<NEXP;e++) m = fmaxf(m, p[e]);
  #pragma unroll
  for (int e=0;e<NEXP;e++) p[e] = __expf(p[e]-m);
  unsigned used = 0; int sel[TOPK]; float sw[TOPK]; float wsum = 0.f;
  #pragma unroll
  for (int k=0;k<TOPK;k++){
    float best = -1.f; int bi = 0;
    #pragma unroll
    for (int e=0;e<NEXP;e++){
      bool ok = (((used>>e)&1u)==0u) && (p[e] > best);
      best = ok ? p[e] : best; bi = ok ? e : bi;
    }
    used |= 1u<<bi; sel[k]=bi; sw[k]=best; wsum += best;
  }
  if (lane==0){
    float inv = 1.f/wsum;
    #pragma unroll
    for (int k=0;k<TOPK;k++){
      ei[t*TOPK+k] = sel[k];
      wv[t*TOPK+k] = sw[k]*inv;
      atomicAdd(&counts[sel[k]], 1);
    }
  }
}

// ---------------- offsets + m-tile worklist ----------------
__global__ void k_offsets(const int* __restrict__ counts, int* __restrict__ offsets,
                          int* __restrict__ mtE, int* __restrict__ mtM0,
                          int* __restrict__ nmt){
  if (threadIdx.x==0 && blockIdx.x==0){
    int s=0;
    for (int e=0;e<NEXP;e++){ offsets[e]=s; s+=counts[e]; }
    offsets[NEXP]=s;
    int nm=0;
    for (int e=0;e<NEXP;e++){
      int ne = counts[e];
      for (int m0=0; m0<ne && nm<MAXMT; m0+=MTILE){ mtE[nm]=e; mtM0[nm]=m0; nm++; }
    }
    nmt[0]=nm;
  }
}

__global__ __launch_bounds__(256) void k_scatter(const int* __restrict__ ei,
                                                 const int* __restrict__ offsets,
                                                 int* __restrict__ cursor,
                                                 int* __restrict__ slot_tk,
                                                 int* __restrict__ tk_slot){
  int g = blockIdx.x*256 + threadIdx.x;
  int e = ei[g];
  int pos = atomicAdd(&cursor[e], 1);
  int slot = offsets[e] + pos;
  slot_tk[slot] = g;
  tk_slot[g] = slot;
}

// ---------------- gate+up GEMM + SiLU ----------------
// tile M=256 x N=32 (both mats), BK=32, 32 K-steps; 8 waves (4m x 2n)
// A (bf16) and B (fp32, source-chunk-swizzled) both staged by global_load_lds, dbuf,
// one barrier per K-step. B converted fp32->bf16 at LDS-read time.
__global__ __launch_bounds__(512,4) void k_gateup(const ushort* __restrict__ xb,
    const float* __restrict__ w1, const float* __restrict__ w3,
    const int* __restrict__ offsets, const int* __restrict__ slot_tk,
    const int* __restrict__ mtE, const int* __restrict__ mtM0, const int* __restrict__ nmt,
    ushort* __restrict__ act){
  int bi  = blockIdx.x;
  int mti = bi / 24;
  int it  = bi - mti*24;
  if (mti >= nmt[0]) return;
  int e    = mtE[mti];
  int m0   = mtM0[mti];
  int off0 = offsets[e];
  int ne   = offsets[e+1]-off0;
  int ibase = it*32;

  __shared__ ushort Als[2][256][32];     // bf16 A tile, linear (conflict-free by 64B stride)
  __shared__ float  Bls[2][2][32][32];   // fp32 B tile, chunk-swizzled content
  __shared__ int toks[256];

  int tid = threadIdx.x, wid = tid>>6, lane = tid&63;
  if (tid < 256){
    int slot = off0 + m0 + tid;
    int fb = slot_tk[off0] >> 2;
    toks[tid] = (m0 + tid < ne) ? (slot_tk[slot] >> 2) : fb;
  }
  __syncthreads();

  // A DMA: 2 rounds; round s: row = s*128 + wid*16 + (lane>>2), chunk lane&3
  const ushort* asrc0 = xb + (size_t)toks[      wid*16 + (lane>>2)]*HDIM + (lane&3)*8;
  const ushort* asrc1 = xb + (size_t)toks[128 + wid*16 + (lane>>2)]*HDIM + (lane&3)*8;
  // B DMA: 1 round; brow = wid*8+(lane>>3) over [2 mats][32 rows]; source chunk XOR-swizzled
  int brow = wid*8 + (lane>>3);
  int bmat = brow>>5, birow = brow&31, bc = lane&7;
  const float* bsrc = (bmat ? w3 : w1) + (size_t)e*IDIM*HDIM
                    + (size_t)(ibase+birow)*HDIM + ((bc ^ (birow&7))<<2);

  int wm = wid>>1, wn = wid&1;
  f32x4 accg[4], accu[4];
  #pragma unroll
  for (int m=0;m<4;m++){ accg[m]=(f32x4){0,0,0,0}; accu[m]=(f32x4){0,0,0,0}; }

  ushort* aDst0 = &Als[0][0][0] + (size_t)(      wid*16)*32;
  ushort* aDst1 = &Als[0][0][0] + (size_t)(128 + wid*16)*32;
  float*  bDst  = &Bls[0][0][0][0] + (size_t)wid*256;
  const size_t aBufStride = 256*32;      // ushorts per A buffer
  const size_t bBufStride = 2*32*32;     // floats per B buffer

  auto stage = [&](int buf, int kb){
    gload_lds16(asrc0 + kb*32, aDst0 + buf*aBufStride);
    gload_lds16(asrc1 + kb*32, aDst1 + buf*aBufStride);
    gload_lds16(bsrc  + kb*32, bDst  + buf*bBufStride);
  };
  int rB = wn*16 + (lane&15);            // B row (i-col) this wave reads
  int q  = lane>>4;
  int c1 = ( 2*q   ) ^ (rB&7);
  int c2 = ( 2*q+1 ) ^ (rB&7);
  auto compute = [&](int buf){
    bf16x8 af[4];
    #pragma unroll
    for (int m=0;m<4;m++)
      af[m] = *(const bf16x8*)(&Als[buf][wm*64 + m*16 + (lane&15)][q*8]);
    #pragma unroll
    for (int mat=0; mat<2; ++mat){
      f32x4 x1 = *(const f32x4*)(&Bls[buf][mat][rB][c1*4]);
      f32x4 x2 = *(const f32x4*)(&Bls[buf][mat][rB][c2*4]);
      bf16x8 b;
      b[0]=(short)f2bf(x1[0]); b[1]=(short)f2bf(x1[1]);
      b[2]=(short)f2bf(x1[2]); b[3]=(short)f2bf(x1[3]);
      b[4]=(short)f2bf(x2[0]); b[5]=(short)f2bf(x2[1]);
      b[6]=(short)f2bf(x2[2]); b[7]=(short)f2bf(x2[3]);
      if (mat==0){
        #pragma unroll
        for (int m=0;m<4;m++) accg[m] = __builtin_amdgcn_mfma_f32_16x16x32_bf16(af[m], b, accg[m], 0,0,0);
      } else {
        #pragma unroll
        for (int m=0;m<4;m++) accu[m] = __builtin_amdgcn_mfma_f32_16x16x32_bf16(af[m], b, accu[m], 0,0,0);
      }
    }
  };

  stage(0, 0);
  __syncthreads();
  for (int kb=0; kb<32; ++kb){
    int cur = kb & 1;
    if (kb+1 < 32) stage(cur^1, kb+1);
    compute(cur);
    __syncthreads();
  }

  int nval = ne - m0; if (nval > 256) nval = 256;
  #pragma unroll
  for (int m=0;m<4;m++)
    #pragma unroll
    for (int r=0;r<4;r++){
      int row = wm*64 + m*16 + (lane>>4)*4 + r;
      if (row < nval){
        float g = accg[m][r], u = accu[m][r];
        float sval = g / (1.f + __expf(-g)) * u;
        act[(size_t)(off0+m0+row)*IDIM + ibase + wn*16 + (lane&15)] = f2bf(sval);
      }
    }
}

// ---------------- down GEMM ----------------
// tile M=256 x N=64, BK=32, 24 K-steps; 8 waves (4m x 2n); same DMA structure
__global__ __launch_bounds__(512,4) void k_down(const ushort* __restrict__ act,
    const float* __restrict__ w2, const int* __restrict__ offsets,
    const int* __restrict__ mtE, const int* __restrict__ mtM0, const int* __restrict__ nmt,
    float* __restrict__ pout){
  int bi  = blockIdx.x;
  int mti = bi >> 4;
  int ht  = bi & 15;
  if (mti >= nmt[0]) return;
  int e    = mtE[mti];
  int m0   = mtM0[mti];
  int off0 = offsets[e], ne = offsets[e+1]-off0;
  int hbase = ht*64;

  __shared__ ushort Als[2][256][32];
  __shared__ float  Bls[2][64][32];

  int tid = threadIdx.x, wid = tid>>6, lane = tid&63;

  int ar0 = m0 +       wid*16 + (lane>>2); ar0 = (ar0 < ne) ? ar0 : (ne-1);
  int ar1 = m0 + 128 + wid*16 + (lane>>2); ar1 = (ar1 < ne) ? ar1 : (ne-1);
  const ushort* asrc0 = act + (size_t)(off0+ar0)*IDIM + (lane&3)*8;
  const ushort* asrc1 = act + (size_t)(off0+ar1)*IDIM + (lane&3)*8;
  int brow = wid*8 + (lane>>3);          // 0..63 h-rows
  int bc   = lane&7;
  const float* bsrc = w2 + (size_t)e*HDIM*IDIM
                    + (size_t)(hbase+brow)*IDIM + ((bc ^ (brow&7))<<2);

  int wm = wid>>1, wn = wid&1;
  f32x4 acc[4][2];
  #pragma unroll
  for (int m=0;m<4;m++)
    #pragma unroll
    for (int n=0;n<2;n++) acc[m][n]=(f32x4){0,0,0,0};

  ushort* aDst0 = &Als[0][0][0] + (size_t)(      wid*16)*32;
  ushort* aDst1 = &Als[0][0][0] + (size_t)(128 + wid*16)*32;
  float*  bDst  = &Bls[0][0][0] + (size_t)wid*256;
  const size_t aBufStride = 256*32;
  const size_t bBufStride = 64*32;

  auto stage = [&](int buf, int kb){
    gload_lds16(asrc0 + kb*32, aDst0 + buf*aBufStride);
    gload_lds16(asrc1 + kb*32, aDst1 + buf*aBufStride);
    gload_lds16(bsrc  + kb*32, bDst  + buf*bBufStride);
  };
  int q = lane>>4;
  auto compute = [&](int buf){
    bf16x8 af[4];
    #pragma unroll
    for (int m=0;m<4;m++)
      af[m] = *(const bf16x8*)(&Als[buf][wm*64 + m*16 + (lane&15)][q*8]);
    #pragma unroll
    for (int n=0;n<2;n++){
      int rB = wn*32 + n*16 + (lane&15);
      int c1 = ( 2*q   ) ^ (rB&7);
      int c2 = ( 2*q+1 ) ^ (rB&7);
      f32x4 x1 = *(const f32x4*)(&Bls[buf][rB][c1*4]);
      f32x4 x2 = *(const f32x4*)(&Bls[buf][rB][c2*4]);
      bf16x8 b;
      b[0]=(short)f2bf(x1[0]); b[1]=(short)f2bf(x1[1]);
      b[2]=(short)f2bf(x1[2]); b[3]=(short)f2bf(x1[3]);
      b[4]=(short)f2bf(x2[0]); b[5]=(short)f2bf(x2[1]);
      b[6]=(short)f2bf(x2[2]); b[7]=(short)f2bf(x2[3]);
      #pragma unroll
      for (int m=0;m<4;m++)
        acc[m][n] = __builtin_amdgcn_mfma_f32_16x16x32_bf16(af[m], b, acc[m][n], 0,0,0);
    }
  };

  stage(0, 0);
  __syncthreads();
  for (int kb=0; kb<24; ++kb){
    int cur = kb & 1;
    if (kb+1 < 24) stage(cur^1, kb+1);
    compute(cur);
    __syncthreads();
  }

  int nval = ne - m0; if (nval > 256) nval = 256;
  #pragma unroll
  for (int m=0;m<4;m++)
    #pragma unroll
    for (int n=0;n<2;n++)
      #pragma unroll
      for (int r=0;r<4;r++){
        int row = wm*64 + m*16 + (lane>>4)*4 + r;
        if (row < nval)
          pout[(size_t)(off0+m0+row)*HDIM + hbase + wn*32 + n*16 + (lane&15)] = acc[m][n][r];
      }
}

// ---------------- combine ----------------
__global__ __launch_bounds__(256) void k_combine(const float* __restrict__ pout,
    const int* __restrict__ tk_slot, const float* __restrict__ wv,
    float* __restrict__ out){
  int t = blockIdx.x;
  int c = threadIdx.x;
  float a0=0,a1=0,a2=0,a3=0;
  #pragma unroll
  for (int k=0;k<TOPK;k++){
    int slot = tk_slot[t*TOPK+k];
    float w  = wv[t*TOPK+k];
    float4 v = *(const float4*)(pout + (size_t)slot*HDIM + c*4);
    a0 = fmaf(w, v.x, a0); a1 = fmaf(w, v.y, a1);
    a2 = fmaf(w, v.z, a2); a3 = fmaf(w, v.w, a3);
  }
  float4 o; o.x=a0; o.y=a1; o.z=a2; o.w=a3;
  *(float4*)(out + (size_t)t*HDIM + c*4) = o;
}

extern "C" void kernel_launch(void* const* d_in, const int* in_sizes, int n_in,
                              void* d_out, int out_size, void* d_ws, size_t ws_size,
                              hipStream_t stream){
  const float* x  = (const float*)d_in[0];
  const float* gw = (const float*)d_in[1];
  const float* w1 = (const float*)d_in[2];
  const float* w3 = (const float*)d_in[3];
  const float* w2 = (const float*)d_in[4];
  float* out = (float*)d_out;

  char* ws = (char*)d_ws;
  size_t off = 0;
  ushort* xb   = (ushort*)(ws + off); off += (size_t)T_TOK*HDIM*2;
  ushort* act  = (ushort*)(ws + off); off += (size_t)NPAIR*IDIM*2;
  float*  pout = (float*) (ws + off); off += (size_t)NPAIR*HDIM*4;
  int* counts  = (int*)(ws + off); off += NEXP*4;
  int* cursor  = (int*)(ws + off); off += NEXP*4;
  int* offsets = (int*)(ws + off); off += (NEXP+1)*4;
  int* mtE     = (int*)(ws + off); off += MAXMT*4;
  int* mtM0    = (int*)(ws + off); off += MAXMT*4;
  int* nmt     = (int*)(ws + off); off += 4;
  off = (off + 255) & ~(size_t)255;
  int*   ei      = (int*)  (ws + off); off += (size_t)NPAIR*4;
  float* wvp     = (float*)(ws + off); off += (size_t)NPAIR*4;
  int*   slot_tk = (int*)  (ws + off); off += (size_t)NPAIR*4;
  int*   tk_slot = (int*)  (ws + off); off += (size_t)NPAIR*4;

  hipMemsetAsync(counts, 0, 2*NEXP*4, stream);

  k_convert_x<<<T_TOK*HDIM/1024, 256, 0, stream>>>(x, xb);
  k_router<<<T_TOK/4, 256, 0, stream>>>(x, gw, ei, wvp, counts);
  k_offsets<<<1, 64, 0, stream>>>(counts, offsets, mtE, mtM0, nmt);
  k_scatter<<<NPAIR/256, 256, 0, stream>>>(ei, offsets, cursor, slot_tk, tk_slot);
  k_gateup<<<MAXMT*24, 512, 0, stream>>>(xb, w1, w3, offsets, slot_tk, mtE, mtM0, nmt, act);
  k_down<<<MAXMT*16, 512, 0, stream>>>(act, w2, offsets, mtE, mtM0, nmt, pout);
  k_combine<<<T_TOK, 256, 0, stream>>>(pout, tk_slot, wvp, out);
}